// Round 1
// baseline (465.526 us; speedup 1.0000x reference)
//
#include <hip/hip_runtime.h>
#include <stdint.h>

// Problem constants (fixed by reference)
#define NB 2048           // batch N
#define NI 256            // input dim I
#define NJ 256            // out dim J
#define GK 300            // grid size K
#define KPAD 320          // K padded to multiple of 32 (10 MFMA-chunks per (i))
#define KK_PER_I (2*KPAD) // cos/sin interleaved: 640 reduction elems per i
#define NKC (NI*KK_PER_I/32)  // 5120 chunks of 32 kk (each chunk = 16 j x 32 kk frag block)
#define SPLITK 16
#define BM 128
#define BN 128

typedef __bf16 bf16x8 __attribute__((ext_vector_type(8)));
typedef __bf16 bf16x2 __attribute__((ext_vector_type(2)));
typedef float  f32x4  __attribute__((ext_vector_type(4)));
typedef __attribute__((address_space(1))) const unsigned int gu32;
typedef __attribute__((address_space(3))) unsigned int lu32;

// cos/sin of `ang` radians via v_cos/v_sin (which take revolutions; explicit fract)
__device__ __forceinline__ void sincos2pi(float ang, float& c, float& s) {
  float r = ang * 0.15915494309189535f;   // 1/(2*pi)
  r = r - floorf(r);
  c = __builtin_amdgcn_cosf(r);
  s = __builtin_amdgcn_sinf(r);
}

// ---------------------------------------------------------------------------
// Pass 1: coeffs fp32 [2][J][I][300] -> bf16 workspace in MFMA fragment order.
// Layout: chunk(kc, jt) = 1KB; within chunk byte = q*256 + n*16 + jj*2 where
// kk_local = q*8 + jj, kk = kc*32 + kk_local, kk = i*640 + k*2 + d,
// j = jt*16 + n. Low bf16 of each uint = cos coeff (d=0), high = sin (d=1).
// One thread per uint (pair). One block = one chunk.
// ---------------------------------------------------------------------------
__global__ __launch_bounds__(256) void convert_b(const float* __restrict__ coeffs,
                                                 unsigned int* __restrict__ bw) {
  const unsigned int tid = blockIdx.x * 256u + threadIdx.x;
  const unsigned int jjpair = tid & 3u;          // pair within 16B lane slot
  const unsigned int n      = (tid >> 2) & 15u;  // j within tile
  const unsigned int q      = (tid >> 6) & 3u;   // lane quad
  const unsigned int jt     = (tid >> 8) & 15u;  // j tile
  const unsigned int kc     = tid >> 12;         // kk chunk
  const unsigned int kk = kc * 32u + q * 8u + jjpair * 2u;
  const unsigned int i  = kk / KK_PER_I;
  const unsigned int k  = (kk % KK_PER_I) >> 1;
  const unsigned int j  = jt * 16u + n;
  unsigned int val = 0u;
  if (k < GK) {
    float c0 = coeffs[(j * NI + i) * GK + k];          // d=0 (cos part)
    float c1 = coeffs[((NJ + j) * NI + i) * GK + k];   // d=1 (sin part)
    bf16x2 p; p.x = (__bf16)c0; p.y = (__bf16)c1;
    val = __builtin_bit_cast(unsigned int, p);
  }
  bw[tid] = val;
}

// ---------------------------------------------------------------------------
// Pass 2: out[n][j] = bias[j]  (float4 vectorized)
// ---------------------------------------------------------------------------
__global__ __launch_bounds__(256) void init_out(const float* __restrict__ bias,
                                                float* __restrict__ out) {
  const int tid = blockIdx.x * 256 + threadIdx.x;     // 131072 float4s
  float4 b = ((const float4*)bias)[tid & 63];
  ((float4*)out)[tid] = b;
}

// ---------------------------------------------------------------------------
// Pass 3: GEMM. C[2048][256] += A[2048][KK] * Bt[256][KK], KK = 163840.
// A generated on the fly (rotation recurrence), B via global_load_lds DMA.
// Grid: 16 m-tiles x 2 n-tiles x 16 k-slices = 512 blocks, 256 thr (4 waves).
// Per iter: BK = 64 kk (= 32 k values, cos+sin interleaved) = 2 MFMA k-steps.
// ---------------------------------------------------------------------------
__global__ __launch_bounds__(256, 2) void fkan_gemm(const float* __restrict__ x,
                                                    const unsigned int* __restrict__ bw,
                                                    float* __restrict__ out) {
  __shared__ uint4 lds4[2048];      // 32 KB: [0,16K) = As (16 chunks), [16K,32K) = Bs
  char* lds = (char*)lds4;

  const int bid = blockIdx.x;
  const int mt = bid & 15;          // m-tile fastest: blocks sharing B slice adjacent
  const int nt = (bid >> 4) & 1;
  const int s  = bid >> 5;          // split-k slice (i range s*16 .. s*16+15)
  const int m0 = mt * BM;

  const int t    = (int)threadIdx.x;
  const int lane = t & 63;
  const int wave = t >> 6;

  // A-generation mapping: thread -> (row-in-tile, m-tile, kc-half)
  const int gn  = t & 15;
  const int gmt = (t >> 4) & 7;
  const int gkc = t >> 7;           // 0/1: which 16-k half of the 32-k window
  const int grow = gmt * 16 + gn;   // 0..127
  const float* xptr = x + (m0 + grow) * NI;
  const unsigned int abase = (unsigned int)((gkc * 8 + gmt) * 1024 + gn * 16);

  // MFMA wave tiling: 2x2 waves, each 64x64 (4x4 tiles of 16x16)
  const int wr = wave >> 1;
  const int wc = wave & 1;

  f32x4 acc[4][4];
  #pragma unroll
  for (int mm = 0; mm < 4; mm++)
    #pragma unroll
    for (int nn = 0; nn < 4; nn++)
      acc[mm][nn] = (f32x4){0.f, 0.f, 0.f, 0.f};

  const int kc0 = s * (NKC / SPLITK);   // s*320 chunks

  #pragma unroll 1
  for (int ii = 0; ii < 16; ii++) {
    const int i = s * 16 + ii;
    const float xv = xptr[i];
    // Seed trig for this i: step (x), iter-advance (32x), thread start angle
    float c1, s1, c32, s32, ccur, scur;
    sincos2pi(xv, c1, s1);
    sincos2pi(32.f * xv, c32, s32);
    sincos2pi(xv * (float)(gkc * 16 + 1), ccur, scur);

    #pragma unroll 1
    for (int t10 = 0; t10 < 10; t10++) {
      __syncthreads();   // previous iter's LDS reads complete

      // ---- A generation: 16 consecutive k per thread via rotation ----
      float cc = ccur, ss = scur;
      #pragma unroll
      for (int q = 0; q < 4; q++) {
        uint4 w;
        #pragma unroll
        for (int p = 0; p < 4; p++) {
          bf16x2 pk; pk.x = (__bf16)cc; pk.y = (__bf16)ss;
          ((unsigned int*)&w)[p] = __builtin_bit_cast(unsigned int, pk);
          float nc = cc * c1 - ss * s1;   // rotate by x
          ss = ss * c1 + cc * s1;
          cc = nc;
        }
        *(uint4*)(lds + abase + q * 256) = w;
      }
      { // advance start angle by 32x for next iter
        float nc = ccur * c32 - scur * s32;
        scur = scur * c32 + ccur * s32;
        ccur = nc;
      }

      // ---- B staging: 16 chunks (2 kc x 8 jt) via width-16 DMA ----
      const int kc = kc0 + ii * (KK_PER_I / 32) + t10 * 2;
      #pragma unroll
      for (int q2 = 0; q2 < 4; q2++) {
        const int idx = wave * 4 + q2;        // 0..15 = kcoff*8 + jtoff
        const int kcoff = idx >> 3;
        const int jtoff = idx & 7;
        const unsigned int* src = bw + ((((kc + kcoff) * 16) + nt * 8 + jtoff) << 8)
                                     + lane * 4;
        unsigned int* dst = (unsigned int*)(lds + 16384 + idx * 1024);
        __builtin_amdgcn_global_load_lds((gu32*)src, (lu32*)dst, 16, 0, 0);
      }

      __syncthreads();   // compiler drains vmcnt+lgkmcnt here

      // ---- MFMA: 2 k-steps x 4x4 tiles per wave ----
      #pragma unroll
      for (int ks = 0; ks < 2; ks++) {
        bf16x8 af[4], bfr[4];
        #pragma unroll
        for (int mm = 0; mm < 4; mm++)
          af[mm] = *(bf16x8*)(lds + (ks * 8 + wr * 4 + mm) * 1024 + lane * 16);
        #pragma unroll
        for (int nn = 0; nn < 4; nn++)
          bfr[nn] = *(bf16x8*)(lds + 16384 + (ks * 8 + wc * 4 + nn) * 1024 + lane * 16);
        #pragma unroll
        for (int mm = 0; mm < 4; mm++)
          #pragma unroll
          for (int nn = 0; nn < 4; nn++)
            acc[mm][nn] = __builtin_amdgcn_mfma_f32_16x16x32_bf16(
                af[mm], bfr[nn], acc[mm][nn], 0, 0, 0);
      }
    }
  }

  // ---- Epilogue: atomic accumulate (C/D layout: col=lane&15, row=quad*4+r) ----
  const int r0 = m0 + wr * 64 + ((lane >> 4) << 2);
  const int c0 = nt * BN + wc * 64 + (lane & 15);
  #pragma unroll
  for (int mm = 0; mm < 4; mm++)
    #pragma unroll
    for (int nn = 0; nn < 4; nn++)
      #pragma unroll
      for (int r = 0; r < 4; r++)
        atomicAdd(&out[(r0 + mm * 16 + r) * NJ + c0 + nn * 16], acc[mm][nn][r]);
}

// ---------------------------------------------------------------------------
extern "C" void kernel_launch(void* const* d_in, const int* in_sizes, int n_in,
                              void* d_out, int out_size, void* d_ws, size_t ws_size,
                              hipStream_t stream) {
  const float* x      = (const float*)d_in[0];   // [2048, 256]
  const float* coeffs = (const float*)d_in[1];   // [2, 256, 256, 300]
  const float* bias   = (const float*)d_in[2];   // [1, 256]
  float* out = (float*)d_out;                    // [2048, 256] fp32
  unsigned int* bw = (unsigned int*)d_ws;        // 83.9 MB bf16 B in fragment order

  // Pass 1: B conversion (ws re-poisoned every call, so always rebuild)
  convert_b<<<dim3(NKC * 16), dim3(256), 0, stream>>>(coeffs, bw);
  // Pass 2: out = bias
  init_out<<<dim3(NB * NJ / 4 / 256), dim3(256), 0, stream>>>(bias, out);
  // Pass 3: GEMM with split-K atomics
  fkan_gemm<<<dim3(16 * 2 * SPLITK), dim3(256), 0, stream>>>(x, bw, out);
}

// Round 2
// 460.050 us; speedup vs baseline: 1.0119x; 1.0119x over previous
//
#include <hip/hip_runtime.h>
#include <stdint.h>

// Problem constants (fixed by reference)
#define NB 2048           // batch N
#define NI 256            // input dim I
#define NJ 256            // out dim J
#define GK 300            // grid size K
#define KPAD 320          // K padded to multiple of 32 (10 MFMA-chunks per (i))
#define KK_PER_I (2*KPAD) // cos/sin interleaved: 640 reduction elems per i
#define NKC (NI*KK_PER_I/32)  // 5120 chunks of 32 kk
#define SPLITK 32
#define II_PER_S (NI / SPLITK)   // 8 i-values per split-k slice
#define BM 128
#define BN 128

typedef __bf16 bf16x8 __attribute__((ext_vector_type(8)));
typedef __bf16 bf16x2 __attribute__((ext_vector_type(2)));
typedef float  f32x4  __attribute__((ext_vector_type(4)));
typedef __attribute__((address_space(1))) const unsigned int gu32;
typedef __attribute__((address_space(3))) unsigned int lu32;

__device__ __forceinline__ void sincos2pi(float ang, float& c, float& s) {
  float r = ang * 0.15915494309189535f;   // 1/(2*pi)
  r = r - floorf(r);
  c = __builtin_amdgcn_cosf(r);
  s = __builtin_amdgcn_sinf(r);
}

// ---------------------------------------------------------------------------
// Pass 1 (v2): coeffs fp32 [2][J][I][300] -> bf16 workspace in MFMA frag order.
// bw uint index = (kc*16+jt)*256 + q*64 + n*16/4 ... byte layout per chunk:
//   byte = q*256 + n*16 + jj*2, kk = kc*32 + q*8 + jj, kk = i*640 + 2k + d,
//   j = jt*16 + n; low bf16 of uint = cos coeff (d=0), high = sin (d=1).
// Key: 4 consecutive k for fixed (j,i) = one contiguous 16B slot, and the
// source offset ((j*256+i)*300 + 4m)*4B is 16B-aligned -> float4 loads.
// Block = (i, jt); thread task = (n, g) with g a 4-k group (80 incl. pad).
// ---------------------------------------------------------------------------
__global__ __launch_bounds__(256) void convert_b(const float* __restrict__ coeffs,
                                                 unsigned int* __restrict__ bw) {
  const int bid = blockIdx.x;
  const int i  = bid >> 4;
  const int jt = bid & 15;
  const int t  = (int)threadIdx.x;
  const int n  = t & 15;
  const int gl = t >> 4;                 // 0..15
  const int j  = jt * 16 + n;

  const float4* r0 = (const float4*)(coeffs + (size_t)(j * NI + i) * GK);
  const float4* r1 = (const float4*)(coeffs + (size_t)((NJ + j) * NI + i) * GK);

  #pragma unroll
  for (int p = 0; p < 5; p++) {
    const int g = p * 16 + gl;           // 0..79 (k-group of 4; >=75 is zero pad)
    uint4 w = {0u, 0u, 0u, 0u};
    if (g < GK / 4) {                    // 75 real groups
      float4 a = r0[g];
      float4 b = r1[g];
      bf16x2 p0; p0.x = (__bf16)a.x; p0.y = (__bf16)b.x;
      bf16x2 p1; p1.x = (__bf16)a.y; p1.y = (__bf16)b.y;
      bf16x2 p2; p2.x = (__bf16)a.z; p2.y = (__bf16)b.z;
      bf16x2 p3; p3.x = (__bf16)a.w; p3.y = (__bf16)b.w;
      w.x = __builtin_bit_cast(unsigned int, p0);
      w.y = __builtin_bit_cast(unsigned int, p1);
      w.z = __builtin_bit_cast(unsigned int, p2);
      w.w = __builtin_bit_cast(unsigned int, p3);
    }
    const int kc = i * 20 + (g >> 2);
    const unsigned int idx = ((unsigned int)(kc * 16 + jt) << 8) + ((g & 3) << 6) + (n << 2);
    *(uint4*)(bw + idx) = w;             // per-wave: 1KB contiguous
  }
}

// ---------------------------------------------------------------------------
// Pass 2: out[n][j] = bias[j]  (float4 vectorized)
// ---------------------------------------------------------------------------
__global__ __launch_bounds__(256) void init_out(const float* __restrict__ bias,
                                                float* __restrict__ out) {
  const int tid = blockIdx.x * 256 + threadIdx.x;     // 131072 float4s
  float4 b = ((const float4*)bias)[tid & 63];
  ((float4*)out)[tid] = b;
}

// ---------------------------------------------------------------------------
// Pass 3: GEMM. C[2048][256] += A[2048][KK] * Bt[256][KK], KK = 163840.
// A generated on the fly (rotation recurrence), B via global_load_lds DMA.
// Grid: 16 m-tiles x 2 n-tiles x 32 k-slices = 1024 blocks (4 blocks/CU).
// ---------------------------------------------------------------------------
__global__ __launch_bounds__(256, 2) void fkan_gemm(const float* __restrict__ x,
                                                    const unsigned int* __restrict__ bw,
                                                    float* __restrict__ out) {
  __shared__ uint4 lds4[2048];      // 32 KB: [0,16K) = As (16 chunks), [16K,32K) = Bs
  char* lds = (char*)lds4;

  const int bid = blockIdx.x;
  const int mt = bid & 15;          // m-tile fastest: blocks sharing B slice adjacent
  const int nt = (bid >> 4) & 1;
  const int s  = bid >> 5;          // split-k slice (i range s*8 .. s*8+7)
  const int m0 = mt * BM;

  const int t    = (int)threadIdx.x;
  const int lane = t & 63;
  const int wave = t >> 6;

  // A-generation mapping: thread -> (row-in-tile, m-tile, kc-half)
  const int gn  = t & 15;
  const int gmt = (t >> 4) & 7;
  const int gkc = t >> 7;           // 0/1: which 16-k half of the 32-k window
  const int grow = gmt * 16 + gn;   // 0..127
  const float* xptr = x + (m0 + grow) * NI;
  const unsigned int abase = (unsigned int)((gkc * 8 + gmt) * 1024 + gn * 16);

  // MFMA wave tiling: 2x2 waves, each 64x64 (4x4 tiles of 16x16)
  const int wr = wave >> 1;
  const int wc = wave & 1;

  f32x4 acc[4][4];
  #pragma unroll
  for (int mm = 0; mm < 4; mm++)
    #pragma unroll
    for (int nn = 0; nn < 4; nn++)
      acc[mm][nn] = (f32x4){0.f, 0.f, 0.f, 0.f};

  const int kc0 = s * (NKC / SPLITK);   // s*160 chunks

  #pragma unroll 1
  for (int ii = 0; ii < II_PER_S; ii++) {
    const int i = s * II_PER_S + ii;
    const float xv = xptr[i];
    // Seed trig for this i: step (x), iter-advance (32x), thread start angle
    float c1, s1, c32, s32, ccur, scur;
    sincos2pi(xv, c1, s1);
    sincos2pi(32.f * xv, c32, s32);
    sincos2pi(xv * (float)(gkc * 16 + 1), ccur, scur);

    #pragma unroll 1
    for (int t10 = 0; t10 < 10; t10++) {
      __syncthreads();   // previous iter's LDS reads complete

      // ---- A generation: 16 consecutive k per thread via rotation ----
      float cc = ccur, ss = scur;
      #pragma unroll
      for (int q = 0; q < 4; q++) {
        uint4 w;
        #pragma unroll
        for (int p = 0; p < 4; p++) {
          bf16x2 pk; pk.x = (__bf16)cc; pk.y = (__bf16)ss;
          ((unsigned int*)&w)[p] = __builtin_bit_cast(unsigned int, pk);
          float nc = cc * c1 - ss * s1;   // rotate by x
          ss = ss * c1 + cc * s1;
          cc = nc;
        }
        *(uint4*)(lds + abase + q * 256) = w;
      }
      { // advance start angle by 32x for next iter
        float nc = ccur * c32 - scur * s32;
        scur = scur * c32 + ccur * s32;
        ccur = nc;
      }

      // ---- B staging: 16 chunks (2 kc x 8 jt) via width-16 DMA ----
      const int kc = kc0 + ii * (KK_PER_I / 32) + t10 * 2;
      #pragma unroll
      for (int q2 = 0; q2 < 4; q2++) {
        const int idx = wave * 4 + q2;        // 0..15 = kcoff*8 + jtoff
        const int kcoff = idx >> 3;
        const int jtoff = idx & 7;
        const unsigned int* src = bw + ((((kc + kcoff) * 16) + nt * 8 + jtoff) << 8)
                                     + lane * 4;
        unsigned int* dst = (unsigned int*)(lds + 16384 + idx * 1024);
        __builtin_amdgcn_global_load_lds((gu32*)src, (lu32*)dst, 16, 0, 0);
      }

      __syncthreads();   // compiler drains vmcnt+lgkmcnt here

      // ---- MFMA: 2 k-steps x 4x4 tiles per wave ----
      #pragma unroll
      for (int ks = 0; ks < 2; ks++) {
        bf16x8 af[4], bfr[4];
        #pragma unroll
        for (int mm = 0; mm < 4; mm++)
          af[mm] = *(bf16x8*)(lds + (ks * 8 + wr * 4 + mm) * 1024 + lane * 16);
        #pragma unroll
        for (int nn = 0; nn < 4; nn++)
          bfr[nn] = *(bf16x8*)(lds + 16384 + (ks * 8 + wc * 4 + nn) * 1024 + lane * 16);
        #pragma unroll
        for (int mm = 0; mm < 4; mm++)
          #pragma unroll
          for (int nn = 0; nn < 4; nn++)
            acc[mm][nn] = __builtin_amdgcn_mfma_f32_16x16x32_bf16(
                af[mm], bfr[nn], acc[mm][nn], 0, 0, 0);
      }
    }
  }

  // ---- Epilogue: atomic accumulate (C/D layout: col=lane&15, row=quad*4+r) ----
  const int r0 = m0 + wr * 64 + ((lane >> 4) << 2);
  const int c0 = nt * BN + wc * 64 + (lane & 15);
  #pragma unroll
  for (int mm = 0; mm < 4; mm++)
    #pragma unroll
    for (int nn = 0; nn < 4; nn++)
      #pragma unroll
      for (int r = 0; r < 4; r++)
        atomicAdd(&out[(r0 + mm * 16 + r) * NJ + c0 + nn * 16], acc[mm][nn][r]);
}

// ---------------------------------------------------------------------------
extern "C" void kernel_launch(void* const* d_in, const int* in_sizes, int n_in,
                              void* d_out, int out_size, void* d_ws, size_t ws_size,
                              hipStream_t stream) {
  const float* x      = (const float*)d_in[0];   // [2048, 256]
  const float* coeffs = (const float*)d_in[1];   // [2, 256, 256, 300]
  const float* bias   = (const float*)d_in[2];   // [1, 256]
  float* out = (float*)d_out;                    // [2048, 256] fp32
  unsigned int* bw = (unsigned int*)d_ws;        // 83.9 MB bf16 B in fragment order

  // Pass 1: B conversion (ws re-poisoned every call, so always rebuild)
  convert_b<<<dim3(NI * 16), dim3(256), 0, stream>>>(coeffs, bw);
  // Pass 2: out = bias
  init_out<<<dim3(NB * NJ / 4 / 256), dim3(256), 0, stream>>>(bias, out);
  // Pass 3: GEMM with split-K atomics
  fkan_gemm<<<dim3(16 * 2 * SPLITK), dim3(256), 0, stream>>>(x, bw, out);
}

// Round 3
// 451.101 us; speedup vs baseline: 1.0320x; 1.0198x over previous
//
#include <hip/hip_runtime.h>
#include <stdint.h>

// Problem constants (fixed by reference)
#define NB 2048           // batch N
#define NI 256            // input dim I
#define NJ 256            // out dim J
#define GK 300            // grid size K
#define KPAD 320          // K padded to multiple of 32 (10 MFMA-chunks per (i))
#define KK_PER_I (2*KPAD) // cos/sin interleaved: 640 reduction elems per i
#define NKC (NI*KK_PER_I/32)  // 5120 chunks of 32 kk
#define SPLITK 32
#define II_PER_S (NI / SPLITK)   // 8 i-values per split-k slice
#define BM 128
#define BN 256

typedef __bf16 bf16x8 __attribute__((ext_vector_type(8)));
typedef __bf16 bf16x2 __attribute__((ext_vector_type(2)));
typedef float  f32x4  __attribute__((ext_vector_type(4)));
typedef __attribute__((address_space(1))) const unsigned int gu32;
typedef __attribute__((address_space(3))) unsigned int lu32;

__device__ __forceinline__ void sincos2pi(float ang, float& c, float& s) {
  float r = ang * 0.15915494309189535f;   // 1/(2*pi)
  r = r - floorf(r);
  c = __builtin_amdgcn_cosf(r);
  s = __builtin_amdgcn_sinf(r);
}

// ---------------------------------------------------------------------------
// Pass 1: coeffs fp32 [2][J][I][300] -> bf16 workspace in MFMA frag order.
// Per-chunk byte = q*256 + n*16 + jj*2, kk = kc*32 + q*8 + jj, kk = i*640+2k+d,
// j = jt*16 + n; low bf16 of uint = cos coeff (d=0), high = sin (d=1).
// 4 consecutive k for fixed (j,i) = one contiguous 16B slot; source float4s
// are 16B-aligned. Reads: 16 full 64B lines/wave; writes: 1KB contig/wave.
// ---------------------------------------------------------------------------
__global__ __launch_bounds__(256) void convert_b(const float* __restrict__ coeffs,
                                                 unsigned int* __restrict__ bw) {
  const int bid = blockIdx.x;
  const int i  = bid >> 4;
  const int jt = bid & 15;
  const int t  = (int)threadIdx.x;
  const int n  = t & 15;
  const int gl = t >> 4;                 // 0..15
  const int j  = jt * 16 + n;

  const float4* r0 = (const float4*)(coeffs + (size_t)(j * NI + i) * GK);
  const float4* r1 = (const float4*)(coeffs + (size_t)((NJ + j) * NI + i) * GK);

  #pragma unroll
  for (int p = 0; p < 5; p++) {
    const int g = p * 16 + gl;           // 0..79 (k-group of 4; >=75 is zero pad)
    uint4 w = {0u, 0u, 0u, 0u};
    if (g < GK / 4) {                    // 75 real groups
      float4 a = r0[g];
      float4 b = r1[g];
      bf16x2 p0; p0.x = (__bf16)a.x; p0.y = (__bf16)b.x;
      bf16x2 p1; p1.x = (__bf16)a.y; p1.y = (__bf16)b.y;
      bf16x2 p2; p2.x = (__bf16)a.z; p2.y = (__bf16)b.z;
      bf16x2 p3; p3.x = (__bf16)a.w; p3.y = (__bf16)b.w;
      w.x = __builtin_bit_cast(unsigned int, p0);
      w.y = __builtin_bit_cast(unsigned int, p1);
      w.z = __builtin_bit_cast(unsigned int, p2);
      w.w = __builtin_bit_cast(unsigned int, p3);
    }
    const int kc = i * 20 + (g >> 2);
    const unsigned int idx = ((unsigned int)(kc * 16 + jt) << 8) + ((g & 3) << 6) + (n << 2);
    *(uint4*)(bw + idx) = w;             // per-wave: 1KB contiguous
  }
}

// ---------------------------------------------------------------------------
// Pass 2: out[n][j] = bias[j]  (float4 vectorized)
// ---------------------------------------------------------------------------
__global__ __launch_bounds__(256) void init_out(const float* __restrict__ bias,
                                                float* __restrict__ out) {
  const int tid = blockIdx.x * 256 + threadIdx.x;     // 131072 float4s
  float4 b = ((const float4*)bias)[tid & 63];
  ((float4*)out)[tid] = b;
}

// ---------------------------------------------------------------------------
// Pass 3: GEMM. C[2048][256] += A[2048][KK] * Bt[256][KK], KK = 163840.
// Block tile 128m x 256n (full J) so A-gen trig is NOT duplicated across
// n-tiles and MFMA-per-barrier doubles. 4 waves, wave tile 64x128
// (acc[4][8]). Grid: 16 m-tiles x 32 k-slices = 512 blocks = 2/CU.
// ---------------------------------------------------------------------------
__global__ __launch_bounds__(256, 2) void fkan_gemm(const float* __restrict__ x,
                                                    const unsigned int* __restrict__ bw,
                                                    float* __restrict__ out) {
  __shared__ uint4 lds4[3072];      // 48 KB: [0,16K) = As (16 chunks), [16K,48K) = Bs (32)
  char* lds = (char*)lds4;

  const int bid = blockIdx.x;
  const int mt = bid & 15;          // m-tile fastest: blocks sharing B slice adjacent
  const int s  = bid >> 4;          // split-k slice (i range s*8 .. s*8+7)
  const int m0 = mt * BM;

  const int t    = (int)threadIdx.x;
  const int lane = t & 63;
  const int wave = t >> 6;

  // A-generation mapping: thread -> (row-in-tile, m-tile, kc-half)
  const int gn  = t & 15;
  const int gmt = (t >> 4) & 7;
  const int gkc = t >> 7;           // 0/1: which 16-k half of the 32-k window
  const int grow = gmt * 16 + gn;   // 0..127
  const float* xptr = x + (m0 + grow) * NI;
  const unsigned int abase = (unsigned int)((gkc * 8 + gmt) * 1024 + gn * 16);

  // MFMA wave tiling: 2x2 waves, wave tile 64m x 128n (4x8 tiles of 16x16)
  const int wr = wave >> 1;
  const int wc = wave & 1;

  f32x4 acc[4][8];
  #pragma unroll
  for (int mm = 0; mm < 4; mm++)
    #pragma unroll
    for (int nn = 0; nn < 8; nn++)
      acc[mm][nn] = (f32x4){0.f, 0.f, 0.f, 0.f};

  const int kc0 = s * (NKC / SPLITK);   // s*160 chunks

  #pragma unroll 1
  for (int ii = 0; ii < II_PER_S; ii++) {
    const int i = s * II_PER_S + ii;
    const float xv = xptr[i];
    // Seed trig for this i: step (x), iter-advance (32x), thread start angle
    float c1, s1, c32, s32, ccur, scur;
    sincos2pi(xv, c1, s1);
    sincos2pi(32.f * xv, c32, s32);
    sincos2pi(xv * (float)(gkc * 16 + 1), ccur, scur);

    #pragma unroll 1
    for (int t10 = 0; t10 < 10; t10++) {
      __syncthreads();   // previous iter's LDS reads complete

      // ---- A generation: 16 consecutive k per thread via rotation ----
      float cc = ccur, ss = scur;
      #pragma unroll
      for (int q = 0; q < 4; q++) {
        uint4 w;
        #pragma unroll
        for (int p = 0; p < 4; p++) {
          bf16x2 pk; pk.x = (__bf16)cc; pk.y = (__bf16)ss;
          ((unsigned int*)&w)[p] = __builtin_bit_cast(unsigned int, pk);
          float nc = cc * c1 - ss * s1;   // rotate by x
          ss = ss * c1 + cc * s1;
          cc = nc;
        }
        *(uint4*)(lds + abase + q * 256) = w;
      }
      { // advance start angle by 32x for next iter
        float nc = ccur * c32 - scur * s32;
        scur = scur * c32 + ccur * s32;
        ccur = nc;
      }

      // ---- B staging: 32 chunks (2 kc x 16 jt) via width-16 DMA ----
      const int kc = kc0 + ii * (KK_PER_I / 32) + t10 * 2;
      #pragma unroll
      for (int q2 = 0; q2 < 8; q2++) {
        const int idx = wave * 8 + q2;        // 0..31 = kcoff*16 + jtoff
        const int kcoff = idx >> 4;
        const int jtoff = idx & 15;
        const unsigned int* src = bw + ((((kc + kcoff) * 16) + jtoff) << 8)
                                     + lane * 4;
        unsigned int* dst = (unsigned int*)(lds + 16384 + idx * 1024);
        __builtin_amdgcn_global_load_lds((gu32*)src, (lu32*)dst, 16, 0, 0);
      }

      __syncthreads();   // compiler drains vmcnt+lgkmcnt here

      // ---- MFMA: 2 k-steps x 4x8 tiles per wave ----
      #pragma unroll
      for (int ks = 0; ks < 2; ks++) {
        bf16x8 af[4];
        #pragma unroll
        for (int mm = 0; mm < 4; mm++)
          af[mm] = *(bf16x8*)(lds + (ks * 8 + wr * 4 + mm) * 1024 + lane * 16);
        #pragma unroll
        for (int nn = 0; nn < 8; nn++) {
          bf16x8 bfr = *(bf16x8*)(lds + 16384 + (ks * 16 + wc * 8 + nn) * 1024 + lane * 16);
          #pragma unroll
          for (int mm = 0; mm < 4; mm++)
            acc[mm][nn] = __builtin_amdgcn_mfma_f32_16x16x32_bf16(
                af[mm], bfr, acc[mm][nn], 0, 0, 0);
        }
      }
    }
  }

  // ---- Epilogue: atomic accumulate (C/D layout: col=lane&15, row=quad*4+r) ----
  const int r0 = m0 + wr * 64 + ((lane >> 4) << 2);
  const int c0 = wc * 128 + (lane & 15);
  #pragma unroll
  for (int mm = 0; mm < 4; mm++)
    #pragma unroll
    for (int nn = 0; nn < 8; nn++)
      #pragma unroll
      for (int r = 0; r < 4; r++)
        atomicAdd(&out[(r0 + mm * 16 + r) * NJ + c0 + nn * 16], acc[mm][nn][r]);
}

// ---------------------------------------------------------------------------
extern "C" void kernel_launch(void* const* d_in, const int* in_sizes, int n_in,
                              void* d_out, int out_size, void* d_ws, size_t ws_size,
                              hipStream_t stream) {
  const float* x      = (const float*)d_in[0];   // [2048, 256]
  const float* coeffs = (const float*)d_in[1];   // [2, 256, 256, 300]
  const float* bias   = (const float*)d_in[2];   // [1, 256]
  float* out = (float*)d_out;                    // [2048, 256] fp32
  unsigned int* bw = (unsigned int*)d_ws;        // 83.9 MB bf16 B in fragment order

  // Pass 1: B conversion (ws re-poisoned every call, so always rebuild)
  convert_b<<<dim3(NI * 16), dim3(256), 0, stream>>>(coeffs, bw);
  // Pass 2: out = bias
  init_out<<<dim3(NB * NJ / 4 / 256), dim3(256), 0, stream>>>(bias, out);
  // Pass 3: GEMM with split-K atomics
  fkan_gemm<<<dim3(16 * SPLITK), dim3(256), 0, stream>>>(x, bw, out);
}

// Round 4
// 435.414 us; speedup vs baseline: 1.0692x; 1.0360x over previous
//
#include <hip/hip_runtime.h>
#include <stdint.h>

// Problem constants (fixed by reference)
#define NB 2048           // batch N
#define NI 256            // input dim I
#define NJ 256            // out dim J
#define GK 300            // grid size K
#define KPAD 320          // K padded to multiple of 32
#define KK_PER_I (2*KPAD) // cos/sin interleaved: 640 reduction elems per i
#define NKC (NI*KK_PER_I/32)  // 5120 chunk-columns of 32 kk
#define CH_PER_I 20       // 32-kk chunks per i
#define SPLITK 32
#define II_PER_S (NI / SPLITK)   // 8 i-values per split-k slice
#define BM 128

typedef __bf16 bf16x8 __attribute__((ext_vector_type(8)));
typedef __bf16 bf16x2 __attribute__((ext_vector_type(2)));
typedef float  f32x4  __attribute__((ext_vector_type(4)));

__device__ __forceinline__ void sincos2pi(float ang, float& c, float& s) {
  float r = ang * 0.15915494309189535f;   // 1/(2*pi)
  r = r - floorf(r);
  c = __builtin_amdgcn_cosf(r);
  s = __builtin_amdgcn_sinf(r);
}

__device__ __forceinline__ unsigned int pkbf(float c, float s) {
  bf16x2 p; p.x = (__bf16)c; p.y = (__bf16)s;
  return __builtin_bit_cast(unsigned int, p);
}

__device__ __forceinline__ void rot(float& c, float& s, float cr, float sr) {
  float nc = c * cr - s * sr;
  s = s * cr + c * sr;
  c = nc;
}

// ---------------------------------------------------------------------------
// Pass 1: coeffs fp32 [2][J][I][300] -> bf16 workspace in MFMA frag order.
// Frag(kc, jt) = 1KB: byte = q*256 + n*16 + jj*2; kk = kc*32 + q*8 + jj;
// kk = i*640 + 2k + d; j = jt*16 + n; uint low bf16 = cos coeff, high = sin.
// ---------------------------------------------------------------------------
__global__ __launch_bounds__(256) void convert_b(const float* __restrict__ coeffs,
                                                 unsigned int* __restrict__ bw) {
  const int bid = blockIdx.x;
  const int i  = bid >> 4;
  const int jt = bid & 15;
  const int t  = (int)threadIdx.x;
  const int n  = t & 15;
  const int gl = t >> 4;                 // 0..15
  const int j  = jt * 16 + n;

  const float4* r0 = (const float4*)(coeffs + (size_t)(j * NI + i) * GK);
  const float4* r1 = (const float4*)(coeffs + (size_t)((NJ + j) * NI + i) * GK);

  #pragma unroll
  for (int p = 0; p < 5; p++) {
    const int g = p * 16 + gl;           // k-group of 4; >=75 is zero pad
    uint4 w = {0u, 0u, 0u, 0u};
    if (g < GK / 4) {
      float4 a = r0[g];
      float4 b = r1[g];
      w.x = pkbf(a.x, b.x);
      w.y = pkbf(a.y, b.y);
      w.z = pkbf(a.z, b.z);
      w.w = pkbf(a.w, b.w);
    }
    const int kc = i * 20 + (g >> 2);
    const unsigned int idx = ((unsigned int)(kc * 16 + jt) << 8) + ((g & 3) << 6) + (n << 2);
    *(uint4*)(bw + idx) = w;             // per-wave: 1KB contiguous
  }
}

// ---------------------------------------------------------------------------
// Pass 2: out[n][j] = bias[j]
// ---------------------------------------------------------------------------
__global__ __launch_bounds__(256) void init_out(const float* __restrict__ bias,
                                                float* __restrict__ out) {
  const int tid = blockIdx.x * 256 + threadIdx.x;     // 131072 float4s
  float4 b = ((const float4*)bias)[tid & 63];
  ((float4*)out)[tid] = b;
}

// ---------------------------------------------------------------------------
// Pass 3: barrier-free GEMM. C[2048][256] += A * Bt, KK = 163840.
// NO LDS, NO __syncthreads. Each lane generates its own MFMA A-fragment via
// in-register rotation (3x rot-by-1 + 1x rot-by-13 per 32-kk chunk per mm).
// B fragments streamed global->VGPR (coalesced dwordx4, lane*16B within a
// 1KB fragment) with a 1-chunk register double buffer -> compiler emits
// partial vmcnt waits, AITER-style. Block 128m x 256n, 4 waves, wave tile
// 64x128 (acc[4][8]). Grid: 16 mt x 32 s = 512 blocks = 2/CU.
// ---------------------------------------------------------------------------
__global__ __launch_bounds__(256, 2) void fkan_gemm(const float* __restrict__ x,
                                                    const uint4* __restrict__ bw4,
                                                    float* __restrict__ out) {
  const int bid = blockIdx.x;
  const int mt = bid & 15;
  const int s  = bid >> 4;          // split-k slice (i range s*8 .. s*8+7)
  const int m0 = mt * BM;

  const int t    = (int)threadIdx.x;
  const int lane = t & 63;
  const int wave = t >> 6;
  const int wr = wave >> 1;         // m half (64 rows)
  const int wc = wave & 1;          // n half (128 cols)
  const int q  = lane >> 4;         // quad -> k sub-block
  const int ln = lane & 15;         // row (A) / col (B) within 16-tile

  f32x4 acc[4][8];
  #pragma unroll
  for (int mm = 0; mm < 4; mm++)
    #pragma unroll
    for (int nn = 0; nn < 8; nn++)
      acc[mm][nn] = (f32x4){0.f, 0.f, 0.f, 0.f};

  // B fragment pointer: frag(kc, jt=wc*8+nn) at uint4 index (kc*16+jt)*64+lane
  const uint4* bptr = bw4 + (size_t)(wc * 8) * 64 + lane;

  int kc = s * (NKC / SPLITK);      // s*160, contiguous through the slice
  uint4 bcur[8], bnxt[8];
  #pragma unroll
  for (int nn = 0; nn < 8; nn++) bcur[nn] = bptr[(size_t)kc * 1024 + nn * 64];

  float stc[4], sts[4], c1a[4], s1a[4], cDa[4], sDa[4];

  #pragma unroll 1
  for (int ii = 0; ii < II_PER_S; ii++) {
    const int i = s * II_PER_S + ii;
    // Per-i, per-m-tile trig seeds. Lane's A rows: m0 + wr*64 + mm*16 + ln.
    #pragma unroll
    for (int mm = 0; mm < 4; mm++) {
      const float xv = x[(m0 + wr * 64 + mm * 16 + ln) * NI + i];
      sincos2pi(xv, c1a[mm], s1a[mm]);          // rotate-by-1 step
      sincos2pi(13.f * xv, cDa[mm], sDa[mm]);   // rotate-by-13 (chunk advance)
      sincos2pi(xv * (float)(q * 4 + 1), stc[mm], sts[mm]);  // state @ k=q*4+1
    }

    #pragma unroll 2
    for (int c = 0; c < CH_PER_I; c++) {
      // Prefetch next chunk's B fragments (consumed next iteration)
      const int kcn = (kc + 1 < NKC) ? kc + 1 : kc;   // clamp final prefetch
      #pragma unroll
      for (int nn = 0; nn < 8; nn++)
        bnxt[nn] = bptr[(size_t)kcn * 1024 + nn * 64];

      // Generate A fragments in registers: lane holds A[m=ln][kk=q*8+jj],
      // jj=2t+d -> [cos,sin] pairs at k = 16*c + q*4 + {1,2,3,4}
      bf16x8 af[4];
      #pragma unroll
      for (int mm = 0; mm < 4; mm++) {
        float cc = stc[mm], ss = sts[mm];
        uint4 u;
        u.x = pkbf(cc, ss);
        rot(cc, ss, c1a[mm], s1a[mm]); u.y = pkbf(cc, ss);
        rot(cc, ss, c1a[mm], s1a[mm]); u.z = pkbf(cc, ss);
        rot(cc, ss, c1a[mm], s1a[mm]); u.w = pkbf(cc, ss);
        rot(cc, ss, cDa[mm], sDa[mm]); stc[mm] = cc; sts[mm] = ss;
        af[mm] = __builtin_bit_cast(bf16x8, u);
      }

      // 32 MFMAs on the previously-loaded chunk
      #pragma unroll
      for (int nn = 0; nn < 8; nn++) {
        const bf16x8 bfr = __builtin_bit_cast(bf16x8, bcur[nn]);
        #pragma unroll
        for (int mm = 0; mm < 4; mm++)
          acc[mm][nn] = __builtin_amdgcn_mfma_f32_16x16x32_bf16(
              af[mm], bfr, acc[mm][nn], 0, 0, 0);
      }

      #pragma unroll
      for (int nn = 0; nn < 8; nn++) bcur[nn] = bnxt[nn];
      kc++;
    }
  }

  // ---- Epilogue: atomic accumulate (C/D layout: col=lane&15, row=q*4+r) ----
  const int r0 = m0 + wr * 64 + q * 4;
  const int c0 = wc * 128 + ln;
  #pragma unroll
  for (int mm = 0; mm < 4; mm++)
    #pragma unroll
    for (int nn = 0; nn < 8; nn++)
      #pragma unroll
      for (int r = 0; r < 4; r++)
        atomicAdd(&out[(r0 + mm * 16 + r) * NJ + c0 + nn * 16], acc[mm][nn][r]);
}

// ---------------------------------------------------------------------------
extern "C" void kernel_launch(void* const* d_in, const int* in_sizes, int n_in,
                              void* d_out, int out_size, void* d_ws, size_t ws_size,
                              hipStream_t stream) {
  const float* x      = (const float*)d_in[0];   // [2048, 256]
  const float* coeffs = (const float*)d_in[1];   // [2, 256, 256, 300]
  const float* bias   = (const float*)d_in[2];   // [1, 256]
  float* out = (float*)d_out;                    // [2048, 256] fp32
  unsigned int* bw = (unsigned int*)d_ws;        // 83.9 MB bf16 B in fragment order

  // Pass 1: B conversion (ws re-poisoned every call, so always rebuild)
  convert_b<<<dim3(NI * 16), dim3(256), 0, stream>>>(coeffs, bw);
  // Pass 2: out = bias
  init_out<<<dim3(NB * NJ / 4 / 256), dim3(256), 0, stream>>>(bias, out);
  // Pass 3: barrier-free GEMM with split-K atomics
  fkan_gemm<<<dim3(16 * SPLITK), dim3(256), 0, stream>>>(x, (const uint4*)bw, out);
}